// Round 11
// baseline (242.549 us; speedup 1.0000x reference)
//
#include <hip/hip_runtime.h>
#include <hip/hip_bf16.h>

typedef _Float16 f16;
typedef _Float16 f16x2 __attribute__((ext_vector_type(2)));
typedef _Float16 f16x4 __attribute__((ext_vector_type(4)));
typedef _Float16 f16x8 __attribute__((ext_vector_type(8)));
typedef __fp16  h16x2 __attribute__((ext_vector_type(2)));
typedef float f32x4 __attribute__((ext_vector_type(4)));

#define B_  4
#define L_  2048
#define D_  4096
#define H_  8
#define BW_ 512
#define M_  (B_*L_)      // 8192
#define CHUNK 128
#define NCH (L_/CHUNK)   // 16
#define LOG2E 1.4426950408889634f

// workspace layout (bytes)
static const size_t OFF_WPK   = 0;                 // packed B frags: 8MB (both gates)
static const size_t OFF_MSP   = 8ull<<20;          // D_ f32 (16KB), pre-scaled by log2e
static const size_t OFF_YLAP  = 9ull<<20;          // M*D f16x2 (yloc,apfx) = 134MB
static const size_t OFF_SUMA  = 144ull<<20;        // B*NCH*D f32 = 1MB
static const size_t OFF_SUMY  = 145ull<<20;
static const size_t OFF_CARRY = 146ull<<20;

__device__ __forceinline__ void gl16(const void* g, void* l) {
    __builtin_amdgcn_global_load_lds(
        (const __attribute__((address_space(1))) unsigned int*)g,
        (__attribute__((address_space(3))) unsigned int*)l, 16, 0, 0);
}

// ---------- prep: pack W^T into MFMA B-fragment order (+ msp2) ----------
// layout: wpk[((h*16 + n32)*8 + kt64)*8 + fidx][lane] : f16x8
//   fidx = g*4 + fn*2 + kk2 ; fragment element e:
//   B[n = n32*32 + fn*16 + (lane&15)][k = kt64*64 + kk2*32 + (lane>>4)*8 + e]
//   where B[n][k] = w[h][k][n]
__global__ __launch_bounds__(256)
void prep_wpack(const float* __restrict__ w_in, const float* __restrict__ w_a,
                const float* __restrict__ a_param,
                f16* __restrict__ wpk, float* __restrict__ msp2) {
    const int kt  = blockIdx.x & 7;
    const int n32 = (blockIdx.x >> 3) & 15;
    const int h   = blockIdx.x >> 7;
    const int tid = threadIdx.x;
    if (blockIdx.x < 16) {                 // folded: msp2[d]
        int d = blockIdx.x * 256 + tid;
        float v = a_param[d];
        msp2[d] = -8.f * log1pf(expf(v)) * LOG2E;
    }
#pragma unroll
    for (int q = 0; q < 2; ++q) {
        int slot = q * 256 + tid;          // 0..511
        int lane = slot & 63;
        int fidx = slot >> 6;              // g*4 + fn*2 + kk2
        int g    = fidx >> 2;
        int fn   = (fidx >> 1) & 1;
        int kk2  = fidx & 1;
        int row = n32 * 32 + fn * 16 + (lane & 15);
        int col = kt * 64 + kk2 * 32 + ((lane >> 4) << 3);
        const float* src = (g ? w_a : w_in) + (size_t)h * BW_ * BW_;
        f16x8 v;
#pragma unroll
        for (int e = 0; e < 8; ++e)
            v[e] = (f16)src[(size_t)(col + e) * BW_ + row];
        size_t o = ((((size_t)(h * 16 + n32) * 8 + kt) * 8) + fidx) * 64 + lane;
        *(f16x8*)(wpk + o * 8) = v;
    }
}

// ---------- fused gate GEMM + epilogue + chunk-local scan ----------
// BM=128 (= one scan chunk), BN=64, BKK=32, NT=16, 4 waves (2x2),
// mfma 16x16x32 f16. A staged DIRECTLY from f32 x via global_load_lds
// (no prep_xh pass), converted to f16 fragments in-register (cvt_pkrtz).
// 3 staging buffers, depth-2 prefetch, counted vmcnt(16/8/0): ~1800cy of
// loads in flight > ~900cy HBM latency. K-tiles permuted so the TWO tiles
// covering cols [n0,n0+64) are processed last (slots 14,15 -> bufs 2,0),
// providing f32 xv for the epilogue from LDS.
#define BM 128
#define BN 64
#define BKK 32
#define NT 16
#define BUFB 16384       // 128 rows x 32 f32 = 16KB per buffer

// LDS: staging buf0 @0, buf1 @16384, buf2 @32768 (48K). Post-loop overlay:
//  om_s[128][66]f16 @0 | xn_s[128][66]f16 @16896 | segA[4][72]f32 @33792 |
//  segY[4][72]f32 @34944 (-> 36096).  rst_s[128]f32 @49152 (outside staging).
#define SMEM_BYTES 49664

__global__ __launch_bounds__(256, 3)
void gemm_gates(const float* __restrict__ x,
                const int*   __restrict__ segpos,
                const f16*   __restrict__ wpk,
                const float* __restrict__ b_in,
                const float* __restrict__ b_a,
                const float* __restrict__ msp2,
                f16x2* __restrict__ ylap,
                float* __restrict__ sumA,
                float* __restrict__ sumY) {
    __shared__ __align__(16) char smem[SMEM_BYTES];
    f16*   om_s = (f16*)smem;                 // [128][66]
    f16*   xn_s = (f16*)(smem + 16896);       // [128][66]
    float* segA = (float*)(smem + 33792);     // [4][72]
    float* segY = (float*)(smem + 34944);     // [4][72]
    float* rst_s= (float*)(smem + 49152);     // [128] (outside staging region)

    const int tid  = threadIdx.x;
    const int n0   = blockIdx.x * BN;         // n-blocks fastest: A-panel L2 reuse
    const int m0   = blockIdx.y * BM;
    const int h    = blockIdx.z;
    const int lane = tid & 63;
    const int wid  = tid >> 6;
    const int wr   = wid >> 1;
    const int wc   = wid & 1;

    f32x4 accX[4][2] = {};
    f32x4 accA[4][2] = {};

    // reset flags -> LDS (region untouched by staging)
    if (tid < BM) rst_s[tid] = (segpos[m0 + tid] == 0) ? 1.f : 0.f;

    // A staging map: f32, source col pre-swizzled; LDS dest linear (m173/m201)
    const int grow  = lane >> 3;
    const int gcolS = (((lane & 7) ^ grow) << 2);          // f32 units
    const float* aSrc = x + (size_t)(m0 + wid * 32 + grow) * D_ + h * BW_ + gcolS;

    // B packed fragment base for this wave: (h, n32 = n0/32 + wc)
    const f16* wbase = wpk + ((size_t)(h * 16) + (n0 >> 5) + wc) * 32768;

    // read-side: byte offset within 128B row (XOR swizzle, per-lane constant)
    const int koff = ((lane >> 4) * 32) ^ ((lane & 7) << 4);
    const int arow = wr * 64 + (lane & 15);
    const int rowb = wr * 64 + ((lane >> 4) << 2);
    const int txo  = ((n0 >> 5) + 2) & (NT - 1);  // tiles 2nb,2nb+1 land last

    f16x8 bfr[3][4];

#define STAGE(T)                                                              \
    {                                                                         \
        const int ktg = ((T) + txo) & (NT - 1);                               \
        float* Asb = (float*)(smem + ((T) % 3) * BUFB);                       \
        _Pragma("unroll")                                                     \
        for (int q = 0; q < 4; ++q)                                           \
            gl16(aSrc + ktg * 32 + (size_t)q * 8 * D_,                        \
                 Asb + (wid * 32 + q * 8) * 32);                              \
        _Pragma("unroll")                                                     \
        for (int g = 0; g < 2; ++g)                                           \
            _Pragma("unroll")                                                 \
            for (int fn = 0; fn < 2; ++fn)                                    \
                bfr[(T) % 3][g * 2 + fn] = *(const f16x8*)(wbase +            \
                    ((size_t)(ktg >> 1) * 8 + g * 4 + fn * 2 + (ktg & 1)) *   \
                        512 + lane * 8);                                      \
    }

    // prologue: stage slots 0,1
    STAGE(0);
    STAGE(1);

#pragma unroll
    for (int t = 0; t < NT; ++t) {
        if (t + 2 < NT) STAGE(t + 2);
        if (t < NT - 2)      asm volatile("s_waitcnt vmcnt(16)" ::: "memory");
        else if (t == NT - 2) asm volatile("s_waitcnt vmcnt(8)" ::: "memory");
        else                  asm volatile("s_waitcnt vmcnt(0)" ::: "memory");
        __builtin_amdgcn_s_barrier();          // all waves' tile t visible
        __builtin_amdgcn_sched_barrier(0);

        const char* Asb = smem + (t % 3) * BUFB;
        f16x8 af[4];
#pragma unroll
        for (int fm = 0; fm < 4; ++fm) {
            const char* rp = Asb + (arow + fm * 16) * 128;
            f32x4 u0 = *(const f32x4*)(rp + koff);
            f32x4 u1 = *(const f32x4*)(rp + (koff ^ 16));
            h16x2 p0 = __builtin_amdgcn_cvt_pkrtz(u0.x, u0.y);
            h16x2 p1 = __builtin_amdgcn_cvt_pkrtz(u0.z, u0.w);
            h16x2 p2 = __builtin_amdgcn_cvt_pkrtz(u1.x, u1.y);
            h16x2 p3 = __builtin_amdgcn_cvt_pkrtz(u1.z, u1.w);
            f16x8 a8;
            a8[0] = (f16)p0[0]; a8[1] = (f16)p0[1];
            a8[2] = (f16)p1[0]; a8[3] = (f16)p1[1];
            a8[4] = (f16)p2[0]; a8[5] = (f16)p2[1];
            a8[6] = (f16)p3[0]; a8[7] = (f16)p3[1];
            af[fm] = a8;
        }
#pragma unroll
        for (int fn = 0; fn < 2; ++fn) {
            f16x8 bx = bfr[t % 3][fn];
            f16x8 ba = bfr[t % 3][2 + fn];
#pragma unroll
            for (int fm = 0; fm < 4; ++fm) {
                accX[fm][fn] = __builtin_amdgcn_mfma_f32_16x16x32_f16(af[fm], bx, accX[fm][fn], 0, 0, 0);
                accA[fm][fn] = __builtin_amdgcn_mfma_f32_16x16x32_f16(af[fm], ba, accA[fm][fn], 0, 0, 0);
            }
        }
        __builtin_amdgcn_sched_barrier(0);
        __builtin_amdgcn_s_barrier();          // reads done before overwrite
    }
#undef STAGE

    // ---- xv harvest (f32): slot 14 -> buf2 holds tile 2nb (ctile<32, wc=0),
    //      slot 15 -> buf0 holds tile 2nb+1 (ctile>=32, wc=1). Wave-uniform.
    const float* AsL = (const float*)(smem + (wc ? 0 : 2 * BUFB));
    float xvv[2][4][4];
#pragma unroll
    for (int fn = 0; fn < 2; ++fn) {
        const int c5 = fn * 16 + (lane & 15);   // col within 32-wide tile
#pragma unroll
        for (int fm = 0; fm < 4; ++fm)
#pragma unroll
            for (int reg = 0; reg < 4; ++reg) {
                const int rowt = rowb + fm * 16 + reg;
                xvv[fn][fm][reg] = AsL[rowt * 32 + (c5 ^ ((rowt & 7) << 2))];
            }
    }
    __syncthreads();   // xv in regs before overlay writes

    // ---- pass A: epilogue math -> om = 1-a (f16) + xn (f16) in LDS ----
    // C/D layout: col = lane&15, row = (lane>>4)*4 + reg  [m89-verified]
    {
#pragma unroll
        for (int fn = 0; fn < 2; ++fn) {
            const int ctile = wc * 32 + fn * 16 + (lane & 15);
            const int d = h * BW_ + n0 + ctile;
            const float bx = b_in[d];
            const float ba = b_a[d];
            const float mspd = msp2[d];
#pragma unroll
            for (int fm = 0; fm < 4; ++fm) {
#pragma unroll
                for (int reg = 0; reg < 4; ++reg) {
                    const int rowt = rowb + fm * 16 + reg;       // 0..127
                    float gxl = accX[fm][fn][reg] + bx;
                    float gal = accA[fm][fn][reg] + ba;
                    float gx = __builtin_amdgcn_rcpf(1.f + __builtin_amdgcn_exp2f(-gxl * LOG2E));
                    float ga = __builtin_amdgcn_rcpf(1.f + __builtin_amdgcn_exp2f(-gal * LOG2E));
                    float a  = __builtin_amdgcn_exp2f(mspd * ga);
                    float a2 = a * a;                            // = exp(2*log_a)
                    float mult = __builtin_amdgcn_sqrtf(1.f + 1e-6f - a2);
                    float rv = rst_s[rowt];
                    a *= (1.f - rv);
                    mult = rv + (1.f - rv) * mult;
                    float xv = xvv[fn][fm][reg];
                    om_s[rowt * 66 + ctile] = (f16)(1.f - a);
                    xn_s[rowt * 66 + ctile] = (f16)(xv * gx * mult);
                }
            }
        }
    }
    __syncthreads();

    // ---- pass B: per-segment (32-step) summaries ----
    const int scol = tid & 63;
    const int sseg = tid >> 6;
    {
        float A = 1.f, yv = 0.f;
#pragma unroll 4
        for (int t = sseg * 32; t < sseg * 32 + 32; ++t) {
            float a  = 1.f - (float)om_s[t * 66 + scol];
            float xn = (float)xn_s[t * 66 + scol];
            yv = fmaf(a, yv, xn);
            A *= a;
        }
        segA[sseg * 72 + scol] = A;
        segY[sseg * 72 + scol] = yv;
    }
    __syncthreads();

    // ---- pass C: carry-in per segment, rewalk, write packed (yloc, apfx) ----
    {
        float cy = 0.f, pA = 1.f;
        for (int s = 0; s < sseg; ++s) {
            float As_ = segA[s * 72 + scol];
            float Ys_ = segY[s * 72 + scol];
            cy = fmaf(As_, cy, Ys_);
            pA *= As_;
        }
        float Arun = 1.f, yv = cy;
        const size_t obase = (size_t)(m0 + sseg * 32) * D_ + h * BW_ + n0 + scol;
#pragma unroll 4
        for (int i = 0; i < 32; ++i) {
            const int t = sseg * 32 + i;
            float a  = 1.f - (float)om_s[t * 66 + scol];
            float xn = (float)xn_s[t * 66 + scol];
            yv = fmaf(a, yv, xn);
            Arun *= a;
            f16x2 p;
            p[0] = (f16)yv;
            p[1] = (f16)(pA * Arun);
            ylap[obase + (size_t)i * D_] = p;
        }
        if (sseg == 3) {
            const int bb = m0 >> 11;             // batch
            const int cc = (m0 & 2047) >> 7;     // chunk in batch
            size_t si = ((size_t)bb * NCH + cc) * D_ + h * BW_ + n0 + scol;
            sumA[si] = pA * Arun;
            sumY[si] = yv;
        }
    }
}

// ---------- scan phase 2: scan over chunk summaries -> carry-in per chunk ----------
__global__ __launch_bounds__(256)
void scan_mid(const float* __restrict__ sumA, const float* __restrict__ sumY,
              float* __restrict__ carry) {
    int d = blockIdx.x * 256 + threadIdx.x;
    int b = blockIdx.y;
    float hcur = 0.f;
#pragma unroll
    for (int c = 0; c < NCH; ++c) {
        size_t si = ((size_t)b * NCH + c) * D_ + d;
        carry[si] = hcur;
        hcur = fmaf(sumA[si], hcur, sumY[si]);
    }
}

// ---------- scan phase 3: elementwise y = yloc + carry * apfx ----------
__global__ __launch_bounds__(256)
void scan_apply(const float* __restrict__ carry, const f16x2* __restrict__ ylap,
                float* __restrict__ y) {
    size_t i4 = (size_t)blockIdx.x * 256 + threadIdx.x;
    const size_t stride = (size_t)gridDim.x * 256;
    const size_t n4 = (size_t)M_ * D_ / 4;
    for (; i4 < n4; i4 += stride) {
        size_t i = i4 * 4;
        size_t row = i >> 12;
        int d = (int)(i & 4095);
        int b = (int)(row >> 11);
        int c = ((int)row & 2047) >> 7;
        const float* cp = carry + (((size_t)(b * NCH + c)) << 12) + d;
        f32x4 cv = *(const f32x4*)cp;
        f16x8 pk = *(const f16x8*)(ylap + i);   // [y0,a0,y1,a1,y2,a2,y3,a3]
        f32x4 o;
        o.x = fmaf(cv.x, (float)pk[1], (float)pk[0]);
        o.y = fmaf(cv.y, (float)pk[3], (float)pk[2]);
        o.z = fmaf(cv.z, (float)pk[5], (float)pk[4]);
        o.w = fmaf(cv.w, (float)pk[7], (float)pk[6]);
        *(f32x4*)(y + i) = o;
    }
}

extern "C" void kernel_launch(void* const* d_in, const int* in_sizes, int n_in,
                              void* d_out, int out_size, void* d_ws, size_t ws_size,
                              hipStream_t stream) {
    const float* x       = (const float*)d_in[0];
    const int*   segpos  = (const int*)d_in[1];
    // d_in[2] = prev_h (unused by reference for L>1 path)
    const float* w_in    = (const float*)d_in[3];
    const float* b_in    = (const float*)d_in[4];
    const float* w_a     = (const float*)d_in[5];
    const float* b_a     = (const float*)d_in[6];
    const float* a_param = (const float*)d_in[7];

    float* y  = (float*)d_out;
    char*  ws = (char*)d_ws;
    f16*   wpk   = (f16*)(ws + OFF_WPK);
    float* msp2  = (float*)(ws + OFF_MSP);
    f16x2* ylap  = (f16x2*)(ws + OFF_YLAP);
    float* sumA  = (float*)(ws + OFF_SUMA);
    float* sumY  = (float*)(ws + OFF_SUMY);
    float* carry = (float*)(ws + OFF_CARRY);

    prep_wpack<<<dim3(1024), 256, 0, stream>>>(w_in, w_a, a_param, wpk, msp2);
    gemm_gates<<<dim3(BW_ / BN, M_ / BM, H_), 256, 0, stream>>>(
        x, segpos, wpk, b_in, b_a, msp2, ylap, sumA, sumY);
    scan_mid<<<dim3(D_ / 256, B_), 256, 0, stream>>>(sumA, sumY, carry);
    scan_apply<<<dim3(4096), 256, 0, stream>>>(carry, ylap, y);
}

// Round 12
// 213.631 us; speedup vs baseline: 1.1354x; 1.1354x over previous
//
#include <hip/hip_runtime.h>
#include <hip/hip_bf16.h>

typedef _Float16 f16;
typedef _Float16 f16x2 __attribute__((ext_vector_type(2)));
typedef _Float16 f16x4 __attribute__((ext_vector_type(4)));
typedef _Float16 f16x8 __attribute__((ext_vector_type(8)));
typedef float f32x4 __attribute__((ext_vector_type(4)));

#define B_  4
#define L_  2048
#define D_  4096
#define H_  8
#define BW_ 512
#define M_  (B_*L_)      // 8192
#define CHUNK 128
#define NCH (L_/CHUNK)   // 16
#define LOG2E 1.4426950408889634f

// workspace layout (bytes)
static const size_t OFF_WPK   = 0;                 // packed B frags: 8MB (both gates)
static const size_t OFF_MSP   = 8ull<<20;          // D_ f32 (16KB), pre-scaled by log2e
static const size_t OFF_XH    = 9ull<<20;          // M*D fp16 = 64MB
static const size_t OFF_YLAP  = 73ull<<20;         // M*D f16x2 (yloc,apfx) = 134MB
static const size_t OFF_SUMA  = 208ull<<20;        // B*NCH*D f32 = 1MB
static const size_t OFF_SUMY  = 209ull<<20;
static const size_t OFF_CARRY = 210ull<<20;

__device__ __forceinline__ void gl16(const void* g, void* l) {
    __builtin_amdgcn_global_load_lds(
        (const __attribute__((address_space(1))) unsigned int*)g,
        (__attribute__((address_space(3))) unsigned int*)l, 16, 0, 0);
}

// ---------- prep (merged): wpack + msp2 (blocks 0..1023) | x->f16 (1024..3071) ----------
// wpk layout: wpk[((h*16 + n32)*8 + kt)*8 + fidx][lane] : f16x8
//   fidx = g*4 + fn*2 + kk2 ;  B[n][k] = w[h][k][n]
//   n = n32*32 + fn*16 + (lane&15), k = kt*64 + kk2*32 + (lane>>4)*8 + e
__global__ __launch_bounds__(256)
void prep_all(const float* __restrict__ w_in, const float* __restrict__ w_a,
              const float* __restrict__ a_param, const float* __restrict__ x,
              f16* __restrict__ wpk, float* __restrict__ msp2,
              f16* __restrict__ xh) {
    const int bid = blockIdx.x;
    const int tid = threadIdx.x;
    if (bid < 1024) {
        const int kt  = bid & 7;
        const int n32 = (bid >> 3) & 15;
        const int h   = bid >> 7;
        if (bid < 16) {                    // folded: msp2[d]
            int d = bid * 256 + tid;
            float v = a_param[d];
            msp2[d] = -8.f * log1pf(expf(v)) * LOG2E;
        }
#pragma unroll
        for (int q = 0; q < 2; ++q) {
            int slot = q * 256 + tid;      // 0..511
            int lane = slot & 63;
            int fidx = slot >> 6;          // g*4 + fn*2 + kk2
            int g    = fidx >> 2;
            int fn   = (fidx >> 1) & 1;
            int kk2  = fidx & 1;
            int row = n32 * 32 + fn * 16 + (lane & 15);
            int col = kt * 64 + kk2 * 32 + ((lane >> 4) << 3);
            const float* src = (g ? w_a : w_in) + (size_t)h * BW_ * BW_;
            f16x8 v;
#pragma unroll
            for (int e = 0; e < 8; ++e)
                v[e] = (f16)src[(size_t)(col + e) * BW_ + row];
            size_t o = ((((size_t)(h * 16 + n32) * 8 + kt) * 8) + fidx) * 64 + lane;
            *(f16x8*)(wpk + o * 8) = v;
        }
    } else {
        size_t i = ((size_t)(bid - 1024) * 256 + tid) * 8;
        const size_t stride = (size_t)2048 * 256 * 8;
        for (; i < (size_t)M_ * D_; i += stride) {
            f32x4 v0 = *(const f32x4*)(x + i);
            f32x4 v1 = *(const f32x4*)(x + i + 4);
            f16x8 hv;
            hv[0] = (f16)v0.x; hv[1] = (f16)v0.y; hv[2] = (f16)v0.z; hv[3] = (f16)v0.w;
            hv[4] = (f16)v1.x; hv[5] = (f16)v1.y; hv[6] = (f16)v1.z; hv[7] = (f16)v1.w;
            *(f16x8*)(xh + i) = hv;
        }
    }
}

// ---------- fused gate GEMM + epilogue + chunk-local scan ----------
// BM=128 (= one scan chunk), BN=64, BKK=64, NT=8, 4 waves (2x2), 16x16x32 f16.
// A: global_load_lds, THREE 16KB buffers, depth-2 prefetch. B: pre-packed reg
// fragments, depth-1 (L2-hot). Counted waits: vmcnt(16) steady / 12 / 0 —
// A(t) has ~2 compute phases of latency cover. K-tiles permuted (txo=+2) so
// the tile covering cols [n0,n0+64) lands in slot 6 -> buf 0 = epilogue xv.
#define BM 128
#define BN 64
#define BKK 64
#define NT (BW_/BKK)     // 8 K-tiles
#define BUFB 16384       // bytes per A staging buffer

// LDS: bufs @0/16384/32768 (48K). Post-loop overlay: om_s[128][66]f16 @0 |
// xn_s[128][66]f16 @16896 | segA[4][72]f32 @33792 | segY[4][72]f32 @34944.
// rst_s[128]f32 @49152 (outside staging).
#define SMEM_BYTES 49664

__global__ __launch_bounds__(256, 3)
void gemm_gates(const f16*   __restrict__ xh,
                const int*   __restrict__ segpos,
                const f16*   __restrict__ wpk,
                const float* __restrict__ b_in,
                const float* __restrict__ b_a,
                const float* __restrict__ msp2,
                f16x2* __restrict__ ylap,
                float* __restrict__ sumA,
                float* __restrict__ sumY) {
    __shared__ __align__(16) char smem[SMEM_BYTES];
    f16*   om_s = (f16*)smem;                 // [128][66]
    f16*   xn_s = (f16*)(smem + 16896);       // [128][66]
    float* segA = (float*)(smem + 33792);     // [4][72]
    float* segY = (float*)(smem + 34944);     // [4][72]
    float* rst_s= (float*)(smem + 49152);     // [128] (outside staging region)

    const int tid  = threadIdx.x;
    const int m0   = blockIdx.x * BM;         // m fastest (R6 grid: FETCH 86MB)
    const int n0   = blockIdx.y * BN;
    const int h    = blockIdx.z;
    const int lane = tid & 63;
    const int wid  = tid >> 6;
    const int wr   = wid >> 1;
    const int wc   = wid & 1;

    f32x4 accX[4][2] = {};
    f32x4 accA[4][2] = {};

    // reset flags -> LDS (region untouched by staging)
    if (tid < BM) rst_s[tid] = (segpos[m0 + tid] == 0) ? 1.f : 0.f;

    // A staging map (source col pre-swizzled; LDS dest linear — m173/m201)
    const int grow  = lane >> 3;
    const int gcolS = (((lane & 7) ^ grow) << 3);
    const f16* aSrc = xh + (size_t)(m0 + wid * 32 + grow) * D_ + h * BW_ + gcolS;

    // B packed fragment base for this wave: (h, n32 = n0/32 + wc)
    const f16* wbase = wpk + ((size_t)(h * 16) + (n0 >> 5) + wc) * 32768;

    const int swz  = (lane & 7) << 3;        // read-side XOR (involution)
    const int kx   = (lane >> 4) << 3;       // 0,8,16,24
    const int arow = wr * 64 + (lane & 15);
    const int rowb = wr * 64 + ((lane >> 4) << 2);
    const int txo  = (n0 >> 6) + 2;          // tile (n0>>6) lands at slot 6 (buf 0)

    f16x8 bfr[2][8];

#define STAGE_A(T)                                                            \
    {                                                                         \
        const int ktg = ((T) + txo) & (NT - 1);                               \
        f16* Asb = (f16*)(smem + ((T) % 3) * BUFB);                           \
        _Pragma("unroll")                                                     \
        for (int q = 0; q < 4; ++q)                                           \
            gl16(aSrc + ktg * BKK + (size_t)q * 8 * D_,                       \
                 &Asb[(wid * 32 + q * 8) * 64]);                              \
    }
#define LOAD_B(T)                                                             \
    {                                                                         \
        const int ktg = ((T) + txo) & (NT - 1);                               \
        const f16* tp = wbase + (size_t)ktg * 4096;                           \
        _Pragma("unroll")                                                     \
        for (int j = 0; j < 8; ++j)                                           \
            bfr[(T) & 1][j] = *(const f16x8*)(tp + j * 512 + lane * 8);       \
    }

    // prologue: A(0), B(0), A(1) — ordering makes steady-state count uniform
    STAGE_A(0);
    LOAD_B(0);
    STAGE_A(1);

#pragma unroll
    for (int t = 0; t < NT; ++t) {
        if (t + 1 < NT) LOAD_B(t + 1);       // 8 vm ops
        if (t + 2 < NT) STAGE_A(t + 2);      // 4 vm ops
        // after B(t): A(t+1)[4] + B(t+1)[8] + A(t+2)[4] = 16 outstanding
        if (t < NT - 2)       asm volatile("s_waitcnt vmcnt(16)" ::: "memory");
        else if (t == NT - 2) asm volatile("s_waitcnt vmcnt(12)" ::: "memory");
        else                  asm volatile("s_waitcnt vmcnt(0)"  ::: "memory");
        __builtin_amdgcn_s_barrier();        // all waves' A(t) visible
        __builtin_amdgcn_sched_barrier(0);

        const f16* Asb = (const f16*)(smem + (t % 3) * BUFB);
#pragma unroll
        for (int kk2 = 0; kk2 < 2; ++kk2) {
            const int kcolS = (kk2 * 32 + kx) ^ swz;
            f16x8 af[4];
#pragma unroll
            for (int fm = 0; fm < 4; ++fm)
                af[fm] = *(const f16x8*)&Asb[(arow + fm * 16) * 64 + kcolS];
#pragma unroll
            for (int fn = 0; fn < 2; ++fn) {
                f16x8 bx = bfr[t & 1][fn * 2 + kk2];
                f16x8 ba = bfr[t & 1][4 + fn * 2 + kk2];
#pragma unroll
                for (int fm = 0; fm < 4; ++fm) {
                    accX[fm][fn] = __builtin_amdgcn_mfma_f32_16x16x32_f16(af[fm], bx, accX[fm][fn], 0, 0, 0);
                    accA[fm][fn] = __builtin_amdgcn_mfma_f32_16x16x32_f16(af[fm], ba, accA[fm][fn], 0, 0, 0);
                }
            }
        }
        __builtin_amdgcn_sched_barrier(0);
        __builtin_amdgcn_s_barrier();        // reads done before next overwrite
    }
#undef STAGE_A
#undef LOAD_B

    // ---- xv harvest: slot 6 (= tile n0>>6) lives in buf 0 ----
    const f16* As1 = (const f16*)smem;
    f16 xvv[2][4][4];
#pragma unroll
    for (int fn = 0; fn < 2; ++fn) {
        const int ctile = wc * 32 + fn * 16 + (lane & 15);
#pragma unroll
        for (int fm = 0; fm < 4; ++fm)
#pragma unroll
            for (int reg = 0; reg < 4; ++reg) {
                const int rowt = rowb + fm * 16 + reg;
                xvv[fn][fm][reg] = As1[rowt * 64 + (ctile ^ ((rowt & 7) << 3))];
            }
    }
    __syncthreads();   // xv in regs before overlay writes

    // ---- pass A: epilogue math -> om = 1-a (f16) + xn (f16) in LDS ----
    // C/D layout: col = lane&15, row = (lane>>4)*4 + reg  [m89-verified]
    {
#pragma unroll
        for (int fn = 0; fn < 2; ++fn) {
            const int ctile = wc * 32 + fn * 16 + (lane & 15);
            const int d = h * BW_ + n0 + ctile;
            const float bx = b_in[d];
            const float ba = b_a[d];
            const float mspd = msp2[d];
#pragma unroll
            for (int fm = 0; fm < 4; ++fm) {
#pragma unroll
                for (int reg = 0; reg < 4; ++reg) {
                    const int rowt = rowb + fm * 16 + reg;       // 0..127
                    float gxl = accX[fm][fn][reg] + bx;
                    float gal = accA[fm][fn][reg] + ba;
                    float gx = __builtin_amdgcn_rcpf(1.f + __builtin_amdgcn_exp2f(-gxl * LOG2E));
                    float ga = __builtin_amdgcn_rcpf(1.f + __builtin_amdgcn_exp2f(-gal * LOG2E));
                    float a  = __builtin_amdgcn_exp2f(mspd * ga);
                    float a2 = a * a;                            // = exp(2*log_a)
                    float mult = __builtin_amdgcn_sqrtf(1.f + 1e-6f - a2);
                    float rv = rst_s[rowt];
                    a *= (1.f - rv);
                    mult = rv + (1.f - rv) * mult;
                    float xv = (float)xvv[fn][fm][reg];
                    om_s[rowt * 66 + ctile] = (f16)(1.f - a);
                    xn_s[rowt * 66 + ctile] = (f16)(xv * gx * mult);
                }
            }
        }
    }
    __syncthreads();

    // ---- pass B: per-segment (32-step) summaries ----
    const int scol = tid & 63;
    const int sseg = tid >> 6;
    {
        float A = 1.f, yv = 0.f;
#pragma unroll 4
        for (int t = sseg * 32; t < sseg * 32 + 32; ++t) {
            float a  = 1.f - (float)om_s[t * 66 + scol];
            float xn = (float)xn_s[t * 66 + scol];
            yv = fmaf(a, yv, xn);
            A *= a;
        }
        segA[sseg * 72 + scol] = A;
        segY[sseg * 72 + scol] = yv;
    }
    __syncthreads();

    // ---- pass C: carry-in per segment, rewalk, write packed (yloc, apfx) ----
    {
        float cy = 0.f, pA = 1.f;
        for (int s = 0; s < sseg; ++s) {
            float As_ = segA[s * 72 + scol];
            float Ys_ = segY[s * 72 + scol];
            cy = fmaf(As_, cy, Ys_);
            pA *= As_;
        }
        float Arun = 1.f, yv = cy;
        const size_t obase = (size_t)(m0 + sseg * 32) * D_ + h * BW_ + n0 + scol;
#pragma unroll 4
        for (int i = 0; i < 32; ++i) {
            const int t = sseg * 32 + i;
            float a  = 1.f - (float)om_s[t * 66 + scol];
            float xn = (float)xn_s[t * 66 + scol];
            yv = fmaf(a, yv, xn);
            Arun *= a;
            f16x2 p;
            p[0] = (f16)yv;
            p[1] = (f16)(pA * Arun);
            ylap[obase + (size_t)i * D_] = p;
        }
        if (sseg == 3) {
            const int bb = m0 >> 11;             // batch
            const int cc = (m0 & 2047) >> 7;     // chunk in batch
            size_t si = ((size_t)bb * NCH + cc) * D_ + h * BW_ + n0 + scol;
            sumA[si] = pA * Arun;
            sumY[si] = yv;
        }
    }
}

// ---------- scan phase 2: scan over chunk summaries -> carry-in per chunk ----------
__global__ __launch_bounds__(256)
void scan_mid(const float* __restrict__ sumA, const float* __restrict__ sumY,
              float* __restrict__ carry) {
    int d = blockIdx.x * 256 + threadIdx.x;
    int b = blockIdx.y;
    float hcur = 0.f;
#pragma unroll
    for (int c = 0; c < NCH; ++c) {
        size_t si = ((size_t)b * NCH + c) * D_ + d;
        carry[si] = hcur;
        hcur = fmaf(sumA[si], hcur, sumY[si]);
    }
}

// ---------- scan phase 3: elementwise y = yloc + carry * apfx ----------
__global__ __launch_bounds__(256)
void scan_apply(const float* __restrict__ carry, const f16x2* __restrict__ ylap,
                float* __restrict__ y) {
    size_t i4 = (size_t)blockIdx.x * 256 + threadIdx.x;
    const size_t stride = (size_t)gridDim.x * 256;
    const size_t n4 = (size_t)M_ * D_ / 4;
    for (; i4 < n4; i4 += stride) {
        size_t i = i4 * 4;
        size_t row = i >> 12;
        int d = (int)(i & 4095);
        int b = (int)(row >> 11);
        int c = ((int)row & 2047) >> 7;
        const float* cp = carry + (((size_t)(b * NCH + c)) << 12) + d;
        f32x4 cv = *(const f32x4*)cp;
        f16x8 pk = *(const f16x8*)(ylap + i);   // [y0,a0,y1,a1,y2,a2,y3,a3]
        f32x4 o;
        o.x = fmaf(cv.x, (float)pk[1], (float)pk[0]);
        o.y = fmaf(cv.y, (float)pk[3], (float)pk[2]);
        o.z = fmaf(cv.z, (float)pk[5], (float)pk[4]);
        o.w = fmaf(cv.w, (float)pk[7], (float)pk[6]);
        *(f32x4*)(y + i) = o;
    }
}

extern "C" void kernel_launch(void* const* d_in, const int* in_sizes, int n_in,
                              void* d_out, int out_size, void* d_ws, size_t ws_size,
                              hipStream_t stream) {
    const float* x       = (const float*)d_in[0];
    const int*   segpos  = (const int*)d_in[1];
    // d_in[2] = prev_h (unused by reference for L>1 path)
    const float* w_in    = (const float*)d_in[3];
    const float* b_in    = (const float*)d_in[4];
    const float* w_a     = (const float*)d_in[5];
    const float* b_a     = (const float*)d_in[6];
    const float* a_param = (const float*)d_in[7];

    float* y  = (float*)d_out;
    char*  ws = (char*)d_ws;
    f16*   wpk   = (f16*)(ws + OFF_WPK);
    float* msp2  = (float*)(ws + OFF_MSP);
    f16*   xh    = (f16*)(ws + OFF_XH);
    f16x2* ylap  = (f16x2*)(ws + OFF_YLAP);
    float* sumA  = (float*)(ws + OFF_SUMA);
    float* sumY  = (float*)(ws + OFF_SUMY);
    float* carry = (float*)(ws + OFF_CARRY);

    prep_all<<<dim3(3072), 256, 0, stream>>>(w_in, w_a, a_param, x, wpk, msp2, xh);
    gemm_gates<<<dim3(M_ / BM, BW_ / BN, H_), 256, 0, stream>>>(
        xh, segpos, wpk, b_in, b_a, msp2, ylap, sumA, sumY);
    scan_mid<<<dim3(D_ / 256, B_), 256, 0, stream>>>(sumA, sumY, carry);
    scan_apply<<<dim3(4096), 256, 0, stream>>>(carry, ylap, y);
}